// Round 1
// baseline (695.602 us; speedup 1.0000x reference)
//
#include <hip/hip_runtime.h>

typedef __bf16 bf16;
typedef __bf16 v8bf __attribute__((ext_vector_type(8)));
typedef float  v4f  __attribute__((ext_vector_type(4)));

__device__ __forceinline__ float sigf(float x){ return 1.0f/(1.0f + __expf(-x)); }

// ---------------------------------------------------------------- weight prep
struct WTab {
  const float* src[14];
  bf16* dst[14];
  int K[14], N[14], boff[14];
};

// transpose-convert: dst[n*K+k] = (bf16) src[k*N+n]
__global__ __launch_bounds__(256) void k_prepw(WTab tab) {
  __shared__ float lds[32][33];
  int bid = blockIdx.x;
  int e = 0;
  #pragma unroll
  for (int i = 1; i < 14; i++) if (tab.boff[i] <= bid) e = i;
  int local = bid - tab.boff[e];
  int K = tab.K[e], N = tab.N[e];
  int nKT = K >> 5;
  int kt = local % nKT, nt = local / nKT;
  int k0 = kt * 32, n0 = nt * 32;
  const float* src = tab.src[e];
  bf16* dst = tab.dst[e];
  int tx = threadIdx.x & 31, ty = threadIdx.x >> 5;
  #pragma unroll
  for (int i = 0; i < 4; i++)
    lds[ty + i*8][tx] = src[(long)(k0 + ty + i*8) * N + n0 + tx];
  __syncthreads();
  #pragma unroll
  for (int i = 0; i < 4; i++)
    dst[(long)(n0 + ty + i*8) * K + k0 + tx] = (bf16)lds[tx][ty + i*8];
}

__global__ void k_biaspack(const float* bg1, const float* bg2, const float* bq,
                           const float* bgate, const float* bsL, const float* b_t,
                           float* bp1, float* bp2, float* bpq, float* bps) {
  int i = blockIdx.x * 256 + threadIdx.x;   // 0..767
  bp1[i] = bg1[i];  bp1[768+i] = 0.f;
  bp2[i] = bg2[i];  bp2[768+i] = 0.f;
  bpq[i] = bq[i];   bpq[768+i] = 0.f; bpq[1536+i] = 0.f; bpq[2304+i] = bgate[i];
  bps[i] = bsL[i];  bps[768+i] = b_t[i];
}

// ---------------------------------------------------------------- layernorms
__global__ __launch_bounds__(256) void k_ln_a(const float* __restrict__ a,
                                              float* __restrict__ out) {
  int row = blockIdx.x;
  const float* x = a + (long)row * 768;
  int t = threadIdx.x;
  float lv[3], s = 0.f, q = 0.f;
  #pragma unroll
  for (int i = 0; i < 3; i++){ lv[i] = x[t + i*256]; s += lv[i]; q += lv[i]*lv[i]; }
  #pragma unroll
  for (int m = 1; m < 64; m <<= 1){ s += __shfl_xor(s, m); q += __shfl_xor(q, m); }
  __shared__ float ls[4], lq[4];
  int w = t >> 6, lane = t & 63;
  if (!lane){ ls[w] = s; lq[w] = q; }
  __syncthreads();
  s = ls[0]+ls[1]+ls[2]+ls[3]; q = lq[0]+lq[1]+lq[2]+lq[3];
  float mean = s * (1.f/768.f);
  float var  = q * (1.f/768.f) - mean*mean;
  float inv  = rsqrtf(var + 1e-5f);
  float* o = out + (long)row * 768;
  #pragma unroll
  for (int i = 0; i < 3; i++) o[t + i*256] = (lv[i] - mean) * inv;
}

__global__ __launch_bounds__(128) void k_ln_s(const float* __restrict__ sIn,
    const float* __restrict__ g1, const float* __restrict__ g2,
    bf16* __restrict__ s1, bf16* __restrict__ s2, bf16* __restrict__ sb) {
  int row = blockIdx.x;
  const float* x = sIn + (long)row * 384;
  int t = threadIdx.x;
  float lv[3], s = 0.f, q = 0.f;
  #pragma unroll
  for (int i = 0; i < 3; i++){ lv[i] = x[t + i*128]; s += lv[i]; q += lv[i]*lv[i]; }
  #pragma unroll
  for (int m = 1; m < 64; m <<= 1){ s += __shfl_xor(s, m); q += __shfl_xor(q, m); }
  __shared__ float ls[2], lq[2];
  int w = t >> 6, lane = t & 63;
  if (!lane){ ls[w] = s; lq[w] = q; }
  __syncthreads();
  s = ls[0] + ls[1]; q = lq[0] + lq[1];
  float mean = s * (1.f/384.f);
  float var  = q * (1.f/384.f) - mean*mean;
  float inv  = rsqrtf(var + 1e-5f);
  long base = (long)row * 384;
  #pragma unroll
  for (int i = 0; i < 3; i++){
    int c = t + i*128;
    float y = (lv[i] - mean) * inv;
    s1[base + c] = (bf16)(y * g1[c]);
    s2[base + c] = (bf16)(y * g2[c]);
    sb[base + c] = (bf16)lv[i];
  }
}

// ------------------------------------------------- z LN + proj -> bias[h,i,j]
__global__ __launch_bounds__(256) void k_zbias(const float* __restrict__ z,
    const float* __restrict__ gz, const float* __restrict__ Wz,
    float* __restrict__ bias) {
  __shared__ float wzs[2048];       // Wz [128][16]
  __shared__ float pb[64][17];
  int t = threadIdx.x;
  for (int i = t; i < 2048; i += 256) wzs[i] = Wz[i];
  int lane = t & 63, wave = t >> 6;
  int sub = lane & 3;
  long posbase = (long)blockIdx.x * 64;
  long pos = posbase + wave*16 + (lane >> 2);
  const float* zp = z + pos * 128 + sub * 32;
  float4 xv[8];
  #pragma unroll
  for (int i = 0; i < 8; i++) xv[i] = reinterpret_cast<const float4*>(zp)[i];
  const float* x = reinterpret_cast<const float*>(xv);
  float4 gv[8];
  #pragma unroll
  for (int i = 0; i < 8; i++) gv[i] = reinterpret_cast<const float4*>(gz + sub*32)[i];
  const float* g = reinterpret_cast<const float*>(gv);
  float s = 0.f, q = 0.f;
  #pragma unroll
  for (int i = 0; i < 32; i++){ s += x[i]; q += x[i]*x[i]; }
  s += __shfl_xor(s, 1); s += __shfl_xor(s, 2);
  q += __shfl_xor(q, 1); q += __shfl_xor(q, 2);
  float mean = s * (1.f/128.f), var = q * (1.f/128.f) - mean*mean;
  float inv = rsqrtf(var + 1e-5f);
  float part[16];
  #pragma unroll
  for (int h = 0; h < 16; h++) part[h] = 0.f;
  __syncthreads();                  // wzs ready
  #pragma unroll
  for (int i = 0; i < 32; i++){
    float zl = (x[i] - mean) * inv * g[i];
    const float* wr = &wzs[(sub*32 + i) * 16];
    #pragma unroll
    for (int h = 0; h < 16; h++) part[h] += zl * wr[h];
  }
  #pragma unroll
  for (int h = 0; h < 16; h++){
    part[h] += __shfl_xor(part[h], 1);
    part[h] += __shfl_xor(part[h], 2);
  }
  int prow = wave*16 + (lane >> 2);
  #pragma unroll
  for (int j = 0; j < 4; j++) pb[prow][sub*4 + j] = part[sub*4 + j];
  __syncthreads();
  int p = t & 63, hb = t >> 6;
  #pragma unroll
  for (int j = 0; j < 4; j++){
    int h = hb*4 + j;
    bias[(long)h * 1048576 + posbase + p] = pb[p][h];
  }
}

// ---------------------------------------------------------------- MFMA GEMM
// C[z] = A[z] @ BT[z]^T (+ biasv[col]) (+ Cin)   A:[M,K] BT:[Nn,K] bf16, C f32
template<int TM, int TN, bool BIASV, bool CIN>
__global__ __launch_bounds__(256) void gemm_bt(
    const bf16* __restrict__ A, const bf16* __restrict__ BT,
    float* C, const float* __restrict__ biasv, const float* Cin,
    int M, int Nn, int K,
    long sA, long sB, long sC, long sCin, long sBias)
{
  constexpr int WM = TM/2, WN = TN/2;
  constexpr int MI = WM/16, NI = WN/16;
  constexpr int LDT = 40;     // 32 + 8 pad
  __shared__ bf16 As[TM*LDT];
  __shared__ bf16 Bs[TN*LDT];
  int z = blockIdx.z;
  A  += (long)z * sA;
  BT += (long)z * sB;
  C  += (long)z * sC;
  if constexpr (CIN)   Cin   += (long)z * sCin;
  if constexpr (BIASV) biasv += (long)z * sBias;
  int m0 = blockIdx.y * TM, n0 = blockIdx.x * TN;
  int t = threadIdx.x, lane = t & 63, w = t >> 6;
  int wr = w >> 1, wc = w & 1;
  v4f acc[MI][NI];
  #pragma unroll
  for (int mi = 0; mi < MI; mi++)
    #pragma unroll
    for (int ni = 0; ni < NI; ni++)
      acc[mi][ni] = (v4f){0.f, 0.f, 0.f, 0.f};

  for (int k0 = 0; k0 < K; k0 += 32) {
    for (int c = t; c < TM*4; c += 256) {
      int r = c >> 2, kk = (c & 3) * 8;
      *reinterpret_cast<float4*>(&As[r*LDT + kk]) =
        *reinterpret_cast<const float4*>(&A[(long)(m0 + r)*K + k0 + kk]);
    }
    for (int c = t; c < TN*4; c += 256) {
      int r = c >> 2, kk = (c & 3) * 8;
      *reinterpret_cast<float4*>(&Bs[r*LDT + kk]) =
        *reinterpret_cast<const float4*>(&BT[(long)(n0 + r)*K + k0 + kk]);
    }
    __syncthreads();
    int krow = (lane >> 4) * 8;
    v8bf af[MI], bfr[NI];
    #pragma unroll
    for (int mi = 0; mi < MI; mi++)
      af[mi] = *reinterpret_cast<const v8bf*>(&As[(wr*WM + mi*16 + (lane & 15))*LDT + krow]);
    #pragma unroll
    for (int ni = 0; ni < NI; ni++)
      bfr[ni] = *reinterpret_cast<const v8bf*>(&Bs[(wc*WN + ni*16 + (lane & 15))*LDT + krow]);
    #pragma unroll
    for (int mi = 0; mi < MI; mi++)
      #pragma unroll
      for (int ni = 0; ni < NI; ni++)
        acc[mi][ni] = __builtin_amdgcn_mfma_f32_16x16x32_bf16(af[mi], bfr[ni], acc[mi][ni], 0, 0, 0);
    __syncthreads();
  }
  int colb = n0 + wc*WN + (lane & 15);
  int rowb = m0 + wr*WM + ((lane >> 4) << 2);
  #pragma unroll
  for (int mi = 0; mi < MI; mi++)
    #pragma unroll
    for (int ni = 0; ni < NI; ni++) {
      int col = colb + ni*16;
      float bv = 0.f;
      if constexpr (BIASV) bv = biasv[col];
      #pragma unroll
      for (int r = 0; r < 4; r++) {
        int row = rowb + mi*16 + r;
        long idx = (long)row * Nn + col;
        float val = acc[mi][ni][r] + bv;
        if constexpr (CIN) val += Cin[idx];
        C[idx] = val;
      }
    }
}

// ---------------------------------------------------------------- elementwise
__global__ void k_adaln_ep(const float* __restrict__ P1, const float* __restrict__ P2,
                           const float* __restrict__ alnr, bf16* __restrict__ out) {
  for (long i = blockIdx.x*(long)blockDim.x + threadIdx.x; i < 786432;
       i += (long)gridDim.x * blockDim.x)
    out[i] = (bf16)(sigf(P1[i]) * alnr[i] + P2[i]);
}

__global__ void k_qkvgpack(const float* __restrict__ qf, const float* __restrict__ kf,
                           const float* __restrict__ vf, float* gf,
                           bf16* __restrict__ qp, bf16* __restrict__ kp,
                           bf16* __restrict__ vp) {
  const float scale = 0.14433756729740643f;  // 1/sqrt(48)
  for (long i = blockIdx.x*(long)blockDim.x + threadIdx.x; i < 786432;
       i += (long)gridDim.x * blockDim.x) {
    int row = (int)(i / 768), c = (int)(i % 768);
    long po = (long)(c / 48) * 65536 + (long)row * 64 + (c % 48);
    qp[po] = (bf16)(qf[i] * scale);
    kp[po] = (bf16)kf[i];
    vp[po] = (bf16)vf[i];
    gf[i] = sigf(gf[i]);
  }
}

__global__ __launch_bounds__(256) void k_vtrans(const bf16* __restrict__ vp,
                                                bf16* __restrict__ vT) {
  __shared__ bf16 tile[64][66];
  int bid = blockIdx.x;
  int h = bid >> 4, i0 = (bid & 15) << 6;
  int t = threadIdx.x;
  for (int l = t; l < 4096; l += 256) {
    int r = l >> 6, d = l & 63;
    tile[r][d] = vp[(long)h*65536 + (long)(i0 + r)*64 + d];
  }
  __syncthreads();
  for (int l = t; l < 4096; l += 256) {
    int d = l >> 6, r = l & 63;
    vT[(long)h*65536 + (long)d*1024 + i0 + r] = tile[r][d];
  }
}

__global__ __launch_bounds__(256) void k_softmax(const float* __restrict__ sc,
                                                 bf16* __restrict__ pr) {
  long row = blockIdx.x;
  const float* sr = sc + row * 1024;
  int t = threadIdx.x;
  float v[4];
  #pragma unroll
  for (int i = 0; i < 4; i++) v[i] = sr[t + i*256];
  float mx = fmaxf(fmaxf(v[0], v[1]), fmaxf(v[2], v[3]));
  #pragma unroll
  for (int m = 1; m < 64; m <<= 1) mx = fmaxf(mx, __shfl_xor(mx, m));
  __shared__ float l1[4], l2[4];
  int w = t >> 6, lane = t & 63;
  if (!lane) l1[w] = mx;
  __syncthreads();
  mx = fmaxf(fmaxf(l1[0], l1[1]), fmaxf(l1[2], l1[3]));
  float sum = 0.f;
  #pragma unroll
  for (int i = 0; i < 4; i++){ v[i] = __expf(v[i] - mx); sum += v[i]; }
  #pragma unroll
  for (int m = 1; m < 64; m <<= 1) sum += __shfl_xor(sum, m);
  if (!lane) l2[w] = sum;
  __syncthreads();
  sum = l2[0] + l2[1] + l2[2] + l2[3];
  float inv = 1.0f / sum;
  bf16* pw = pr + row * 1024;
  #pragma unroll
  for (int i = 0; i < 4; i++) pw[t + i*256] = (bf16)(v[i] * inv);
}

__global__ void k_go(const float* __restrict__ gf, const float* __restrict__ o,
                     bf16* __restrict__ go) {
  for (long i = blockIdx.x*(long)blockDim.x + threadIdx.x; i < 786432;
       i += (long)gridDim.x * blockDim.x) {
    int row = (int)(i / 768), c = (int)(i % 768);
    go[i] = (bf16)(gf[i] * o[(long)(c / 48)*65536 + (long)row*64 + (c % 48)]);
  }
}

__global__ void k_bmid(const float* __restrict__ x1, const float* __restrict__ x2,
                       bf16* __restrict__ bm) {
  for (long i = blockIdx.x*(long)blockDim.x + threadIdx.x; i < 1572864;
       i += (long)gridDim.x * blockDim.x) {
    float x = x1[i];
    bm[i] = (bf16)(x * sigf(x) * x2[i]);
  }
}

__global__ void k_final(const float* __restrict__ sg, const float* __restrict__ opj,
                        const float* __restrict__ tpj, float* __restrict__ out) {
  for (long i = blockIdx.x*(long)blockDim.x + threadIdx.x; i < 786432;
       i += (long)gridDim.x * blockDim.x)
    out[i] = sigf(sg[i]) * opj[i] + sigf(sg[786432 + i]) * tpj[i];
}

// ---------------------------------------------------------------- launcher
extern "C" void kernel_launch(void* const* d_in, const int* in_sizes, int n_in,
                              void* d_out, int out_size, void* d_ws, size_t ws_size,
                              hipStream_t stream)
{
  const float* A_in  = (const float*)d_in[0];
  const float* S_in  = (const float*)d_in[1];
  const float* Z_in  = (const float*)d_in[2];
  const float* g_s1  = (const float*)d_in[3];
  const float* Wg1   = (const float*)d_in[4];
  const float* bg1   = (const float*)d_in[5];
  const float* Wadd1 = (const float*)d_in[6];
  const float* g_z   = (const float*)d_in[7];
  const float* Wz    = (const float*)d_in[8];
  const float* Wq    = (const float*)d_in[9];
  const float* bq    = (const float*)d_in[10];
  const float* Wk    = (const float*)d_in[11];
  const float* Wv    = (const float*)d_in[12];
  const float* Wgate = (const float*)d_in[13];
  const float* bgate = (const float*)d_in[14];
  const float* Wo    = (const float*)d_in[15];
  const float* bo    = (const float*)d_in[16];
  const float* WsL   = (const float*)d_in[17];
  const float* bsL   = (const float*)d_in[18];
  const float* g_s2  = (const float*)d_in[19];
  const float* Wg2   = (const float*)d_in[20];
  const float* bg2   = (const float*)d_in[21];
  const float* Wadd2 = (const float*)d_in[22];
  const float* W1    = (const float*)d_in[23];
  const float* W2    = (const float*)d_in[24];
  const float* Wb    = (const float*)d_in[25];
  const float* WsT   = (const float*)d_in[26];
  const float* b_t   = (const float*)d_in[27];
  float* OUT = (float*)d_out;

  char* ws = (char*)d_ws;
  size_t off = 0;
  auto alloc = [&](size_t bytes) -> void* {
    void* p = ws + off; off += (bytes + 255) & ~(size_t)255; return p; };

  bf16*  wGA1  = (bf16*) alloc(2ul*294912*2);
  bf16*  wGA2  = (bf16*) alloc(2ul*294912*2);
  bf16*  wQKVG = (bf16*) alloc(4ul*589824*2);
  bf16*  wWoT  = (bf16*) alloc(589824ul*2);
  bf16*  wWsP  = (bf16*) alloc(2ul*294912*2);
  bf16*  wW12  = (bf16*) alloc(2ul*1179648*2);
  bf16*  wWbT  = (bf16*) alloc(1179648ul*2);
  float* bp1   = (float*)alloc(1536*4);
  float* bp2   = (float*)alloc(1536*4);
  float* bpq   = (float*)alloc(3072*4);
  float* bps   = (float*)alloc(1536*4);
  bf16*  sl1   = (bf16*) alloc(393216ul*2);
  bf16*  sl2   = (bf16*) alloc(393216ul*2);
  bf16*  sbf   = (bf16*) alloc(393216ul*2);
  float* alnr  = (float*)alloc(786432ul*4);
  float* P1    = (float*)alloc(786432ul*4);
  float* P2    = (float*)alloc(786432ul*4);   // adjacent to P1
  bf16*  aln   = (bf16*) alloc(786432ul*2);
  bf16*  a2b   = (bf16*) alloc(786432ul*2);
  float* qf    = (float*)alloc(786432ul*4);   // qf,kf,vf,gf adjacent
  float* kf    = (float*)alloc(786432ul*4);
  float* vf    = (float*)alloc(786432ul*4);
  float* gf    = (float*)alloc(786432ul*4);
  bf16*  qp    = (bf16*) alloc(1048576ul*2);  // qp,kp,vp adjacent
  bf16*  kp    = (bf16*) alloc(1048576ul*2);
  bf16*  vp    = (bf16*) alloc(1048576ul*2);
  bf16*  vT    = (bf16*) alloc(1048576ul*2);
  float* bias  = (float*)alloc(16777216ul*4); // [16,1024,1024] scores in-place
  bf16*  probs = (bf16*) alloc(16777216ul*2);
  float* obuf  = (float*)alloc(1048576ul*4);  // [16,1024,64]
  bf16*  gob   = (bf16*) alloc(786432ul*2);
  float* opj   = (float*)alloc(786432ul*4);
  float* sg    = (float*)alloc(2ul*786432*4);
  float* x12   = (float*)alloc(2ul*1572864*4);
  bf16*  bmid  = (bf16*) alloc(1572864ul*2);
  float* tpj   = (float*)alloc(786432ul*4);

  WTab tab;
  auto setw = [&](int i, const float* src, bf16* dst, int K, int N){
    tab.src[i] = src; tab.dst[i] = dst; tab.K[i] = K; tab.N[i] = N; };
  setw(0,  Wg1,   wGA1,            384,  768);
  setw(1,  Wadd1, wGA1 + 294912,   384,  768);
  setw(2,  Wg2,   wGA2,            384,  768);
  setw(3,  Wadd2, wGA2 + 294912,   384,  768);
  setw(4,  Wq,    wQKVG,           768,  768);
  setw(5,  Wk,    wQKVG + 589824,  768,  768);
  setw(6,  Wv,    wQKVG + 2*589824,768,  768);
  setw(7,  Wgate, wQKVG + 3*589824,768,  768);
  setw(8,  Wo,    wWoT,            768,  768);
  setw(9,  WsL,   wWsP,            384,  768);
  setw(10, WsT,   wWsP + 294912,   384,  768);
  setw(11, W1,    wW12,            768, 1536);
  setw(12, W2,    wW12 + 1179648,  768, 1536);
  setw(13, Wb,    wWbT,           1536,  768);
  int boff = 0;
  for (int i = 0; i < 14; i++){ tab.boff[i] = boff; boff += (tab.K[i]/32)*(tab.N[i]/32); }

  k_prepw<<<boff, 256, 0, stream>>>(tab);
  k_biaspack<<<3, 256, 0, stream>>>(bg1, bg2, bq, bgate, bsL, b_t, bp1, bp2, bpq, bps);
  k_ln_a<<<1024, 256, 0, stream>>>(A_in, alnr);
  k_ln_s<<<1024, 128, 0, stream>>>(S_in, g_s1, g_s2, sl1, sl2, sbf);
  (void)hipMemsetAsync(qp, 0, 3ul*1048576*2, stream);  // zero-pad d=48..63
  k_zbias<<<16384, 256, 0, stream>>>(Z_in, g_z, Wz, bias);

  // adaLN branch 1 -> aln ; branch 2 -> a2
  gemm_bt<128,128,true,false><<<dim3(6,8,2), 256, 0, stream>>>(
      sl1, wGA1, P1, bp1, nullptr, 1024, 768, 384, 0, 294912, 786432, 0, 768);
  k_adaln_ep<<<768, 256, 0, stream>>>(P1, P2, alnr, aln);
  gemm_bt<128,128,true,false><<<dim3(6,8,2), 256, 0, stream>>>(
      sl2, wGA2, P1, bp2, nullptr, 1024, 768, 384, 0, 294912, 786432, 0, 768);
  k_adaln_ep<<<768, 256, 0, stream>>>(P1, P2, alnr, a2b);

  // q,k,v,gate projections (z=4 batched)
  gemm_bt<128,128,true,false><<<dim3(6,8,4), 256, 0, stream>>>(
      aln, wQKVG, qf, bpq, nullptr, 1024, 768, 768, 0, 589824, 786432, 0, 768);
  k_qkvgpack<<<768, 256, 0, stream>>>(qf, kf, vf, gf, qp, kp, vp);
  k_vtrans<<<256, 256, 0, stream>>>(vp, vT);

  // scores = q*scale @ k^T + bias (in-place into bias buffer), per head
  gemm_bt<128,128,false,true><<<dim3(8,8,16), 256, 0, stream>>>(
      qp, kp, bias, nullptr, bias, 1024, 1024, 64, 65536, 65536, 1048576, 1048576, 0);
  k_softmax<<<16384, 256, 0, stream>>>(bias, probs);
  gemm_bt<128,64,false,false><<<dim3(1,8,16), 256, 0, stream>>>(
      probs, vT, obuf, nullptr, nullptr, 1024, 64, 1024, 1048576, 65536, 65536, 0, 0);
  k_go<<<768, 256, 0, stream>>>(gf, obuf, gob);
  gemm_bt<128,128,true,false><<<dim3(6,8,1), 256, 0, stream>>>(
      gob, wWoT, opj, bo, nullptr, 1024, 768, 768, 0, 0, 0, 0, 0);
  gemm_bt<128,128,true,false><<<dim3(6,8,2), 256, 0, stream>>>(
      sbf, wWsP, sg, bps, nullptr, 1024, 768, 384, 0, 294912, 786432, 0, 768);

  // transition
  gemm_bt<128,128,false,false><<<dim3(12,8,2), 256, 0, stream>>>(
      a2b, wW12, x12, nullptr, nullptr, 1024, 1536, 768, 0, 1179648, 1572864, 0, 0);
  k_bmid<<<1536, 256, 0, stream>>>(x12, x12 + 1572864, bmid);
  gemm_bt<128,128,false,false><<<dim3(6,8,1), 256, 0, stream>>>(
      bmid, wWbT, tpj, nullptr, nullptr, 1024, 768, 1536, 0, 0, 0, 0, 0);
  k_final<<<768, 256, 0, stream>>>(sg, opj, tpj, OUT);
}